// Round 2
// baseline (151.460 us; speedup 1.0000x reference)
//
#include <hip/hip_runtime.h>
#include <math.h>

#define BN_EPS 1e-5f

// ---------------------------------------------------------------------------
// Shared GEMM body: out[m][n] = epilogue( sum_k X[m][k] * W[n][k] )
// X: [M,K] row-major, W: [N,K] row-major (i.e. computes X @ W^T).
// Tile: 32 (m) x 64 (n), k-chunk 32, 256 threads, 2x4 outputs/thread.
// LDS staged transposed (k-major) so compute reads are vector b64/b128.
// mode: 0 = bias+BN+relu, 1 = bias+relu, 2 = bias only, 3 = none
// ---------------------------------------------------------------------------
__device__ __forceinline__ void gemm_body(
    const float* __restrict__ X, const float* __restrict__ W,
    const float* __restrict__ bias,
    const float* __restrict__ bn_g, const float* __restrict__ bn_b,
    const float* __restrict__ bn_m, const float* __restrict__ bn_v,
    float* __restrict__ out, int K, int ldo, int mode,
    float (*As)[36], float (*Bs)[68])
{
    const int t  = threadIdx.x;
    const int m0 = blockIdx.y * 32;
    const int n0 = blockIdx.x * 64;
    const int tx = t & 15;          // n quad index (0..15) -> n = n0 + 4*tx
    const int ty = t >> 4;          // m pair index (0..15) -> m = m0 + 2*ty
    const int lrow = t >> 3;        // staging row 0..31
    const int lk4  = (t & 7) << 2;  // staging k offset 0,4,...,28

    float acc[2][4];
    #pragma unroll
    for (int i = 0; i < 2; ++i)
        #pragma unroll
        for (int j = 0; j < 4; ++j) acc[i][j] = 0.f;

    for (int kc = 0; kc < K; kc += 32) {
        const float4 av = *(const float4*)&X[(m0 + lrow) * K + kc + lk4];
        const float4 bv0 = *(const float4*)&W[(n0 + lrow) * K + kc + lk4];
        const float4 bv1 = *(const float4*)&W[(n0 + lrow + 32) * K + kc + lk4];

        As[lk4 + 0][lrow] = av.x;
        As[lk4 + 1][lrow] = av.y;
        As[lk4 + 2][lrow] = av.z;
        As[lk4 + 3][lrow] = av.w;
        Bs[lk4 + 0][lrow] = bv0.x;
        Bs[lk4 + 1][lrow] = bv0.y;
        Bs[lk4 + 2][lrow] = bv0.z;
        Bs[lk4 + 3][lrow] = bv0.w;
        Bs[lk4 + 0][lrow + 32] = bv1.x;
        Bs[lk4 + 1][lrow + 32] = bv1.y;
        Bs[lk4 + 2][lrow + 32] = bv1.z;
        Bs[lk4 + 3][lrow + 32] = bv1.w;
        __syncthreads();

        #pragma unroll
        for (int k = 0; k < 32; ++k) {
            const float2 a = *(const float2*)&As[k][ty * 2];
            const float4 b = *(const float4*)&Bs[k][tx * 4];
            acc[0][0] = fmaf(a.x, b.x, acc[0][0]);
            acc[0][1] = fmaf(a.x, b.y, acc[0][1]);
            acc[0][2] = fmaf(a.x, b.z, acc[0][2]);
            acc[0][3] = fmaf(a.x, b.w, acc[0][3]);
            acc[1][0] = fmaf(a.y, b.x, acc[1][0]);
            acc[1][1] = fmaf(a.y, b.y, acc[1][1]);
            acc[1][2] = fmaf(a.y, b.z, acc[1][2]);
            acc[1][3] = fmaf(a.y, b.w, acc[1][3]);
        }
        __syncthreads();
    }

    const int n = n0 + tx * 4;
    #pragma unroll
    for (int i = 0; i < 2; ++i) {
        const int m = m0 + ty * 2 + i;
        float v[4];
        #pragma unroll
        for (int j = 0; j < 4; ++j) v[j] = acc[i][j];
        if (mode == 0) {
            #pragma unroll
            for (int j = 0; j < 4; ++j) {
                float z = v[j] + bias[n + j];
                z = bn_g[n + j] * (z - bn_m[n + j]) * rsqrtf(bn_v[n + j] + BN_EPS) + bn_b[n + j];
                v[j] = fmaxf(z, 0.f);
            }
        } else if (mode == 1) {
            #pragma unroll
            for (int j = 0; j < 4; ++j) v[j] = fmaxf(v[j] + bias[n + j], 0.f);
        } else if (mode == 2) {
            #pragma unroll
            for (int j = 0; j < 4; ++j) v[j] = v[j] + bias[n + j];
        }
        float4 o = make_float4(v[0], v[1], v[2], v[3]);
        *(float4*)&out[m * ldo + n] = o;
    }
}

// One launch computes h (BN+relu), A (=x@Ws1_a^T + bs1) and C (=x@Ws1_b^T)
// selected by blockIdx.z. All share M=512, N=512, K=256, X=x.
__global__ __launch_bounds__(256) void fused3_gemm(
    const float* __restrict__ x,
    const float* __restrict__ W1, const float* __restrict__ b1,
    const float* __restrict__ g, const float* __restrict__ be,
    const float* __restrict__ mu, const float* __restrict__ va,
    const float* __restrict__ Wa, const float* __restrict__ bs1,
    const float* __restrict__ Wb,
    float* __restrict__ h, float* __restrict__ A, float* __restrict__ C)
{
    __shared__ float As[32][36];
    __shared__ float Bs[32][68];
    const int z = blockIdx.z;
    if (z == 0)
        gemm_body(x, W1, b1, g, be, mu, va, h, 256, 512, 0, As, Bs);
    else if (z == 1)
        gemm_body(x, Wa, bs1, nullptr, nullptr, nullptr, nullptr, A, 256, 512, 2, As, Bs);
    else
        gemm_body(x, Wb, nullptr, nullptr, nullptr, nullptr, nullptr, C, 256, 512, 3, As, Bs);
}

// h2 = relu(h @ W2^T + b2), M=512, N=256, K=512
__global__ __launch_bounds__(256) void gemm_h2_kernel(
    const float* __restrict__ h, const float* __restrict__ W2,
    const float* __restrict__ b2, float* __restrict__ h2)
{
    __shared__ float As[32][36];
    __shared__ float Bs[32][68];
    gemm_body(h, W2, b2, nullptr, nullptr, nullptr, nullptr, h2, 512, 256, 1, As, Bs);
}

// scores = h2 @ W3^T + b3 ; softmax -> probs. One wave per row.
__global__ __launch_bounds__(256) void head_kernel(
    const float* __restrict__ h2, const float* __restrict__ W3,
    const float* __restrict__ b3, float* __restrict__ out)
{
    const int t = threadIdx.x;
    const int lane = t & 63;
    const int r = blockIdx.x * 4 + (t >> 6);

    float p[10];
    #pragma unroll
    for (int q = 0; q < 10; ++q) p[q] = 0.f;

    #pragma unroll
    for (int kk = 0; kk < 4; ++kk) {
        const int k = lane + kk * 64;
        const float hv = h2[r * 256 + k];
        #pragma unroll
        for (int q = 0; q < 10; ++q)
            p[q] = fmaf(hv, W3[q * 256 + k], p[q]);
    }
    #pragma unroll
    for (int q = 0; q < 10; ++q) {
        #pragma unroll
        for (int off = 32; off > 0; off >>= 1)
            p[q] += __shfl_down(p[q], off);
    }
    if (lane == 0) {
        float s[10], m = -1e30f;
        #pragma unroll
        for (int q = 0; q < 10; ++q) { s[q] = p[q] + b3[q]; m = fmaxf(m, s[q]); }
        float e[10], sum = 0.f;
        #pragma unroll
        for (int q = 0; q < 10; ++q) { e[q] = __expf(s[q] - m); sum += e[q]; }
        const float inv = 1.f / sum;
        #pragma unroll
        for (int q = 0; q < 10; ++q) {
            out[r * 10 + q] = e[q] * inv;          // pattern_probs
            out[5120 + r * 10 + q] = s[q];         // pattern_scores
        }
    }
}

// similarities: for i<j, sigmoid( sum_k relu(A[i,k]+C[j,k]) * ws2[k] + bs2 )
// written to S[i][j] and S[j][i]; diagonal = 0.  (bs1 already folded into A.)
// Triangle-only grid: block b -> (it <= jt), 32x32 pair tile, 2x2 per thread.
__global__ __launch_bounds__(256) void sim_kernel(
    const float* __restrict__ A, const float* __restrict__ C,
    const float* __restrict__ ws2, const float* __restrict__ bs2,
    float* __restrict__ S)
{
    __shared__ float As[32][36];
    __shared__ float Cs[32][36];
    __shared__ float wsh[512];

    const int t = threadIdx.x;
    const int b = blockIdx.x;
    int jt = 0;
    while ((jt + 1) * (jt + 2) / 2 <= b) ++jt;
    const int it = b - jt * (jt + 1) / 2;
    const int i0 = it * 32, j0 = jt * 32;

    wsh[t] = ws2[t];
    wsh[t + 256] = ws2[t + 256];

    const int tx = t & 15, ty = t >> 4;
    const int lrow = t >> 3, lk4 = (t & 7) << 2;

    float acc[2][2] = {{0.f, 0.f}, {0.f, 0.f}};

    for (int kc = 0; kc < 512; kc += 32) {
        const float4 av = *(const float4*)&A[(i0 + lrow) * 512 + kc + lk4];
        const float4 cv = *(const float4*)&C[(j0 + lrow) * 512 + kc + lk4];
        As[lk4 + 0][lrow] = av.x;
        As[lk4 + 1][lrow] = av.y;
        As[lk4 + 2][lrow] = av.z;
        As[lk4 + 3][lrow] = av.w;
        Cs[lk4 + 0][lrow] = cv.x;
        Cs[lk4 + 1][lrow] = cv.y;
        Cs[lk4 + 2][lrow] = cv.z;
        Cs[lk4 + 3][lrow] = cv.w;
        __syncthreads();

        #pragma unroll
        for (int k = 0; k < 32; ++k) {
            const float2 a = *(const float2*)&As[k][ty * 2];
            const float2 c = *(const float2*)&Cs[k][tx * 2];
            const float w = wsh[kc + k];
            acc[0][0] = fmaf(fmaxf(a.x + c.x, 0.f), w, acc[0][0]);
            acc[0][1] = fmaf(fmaxf(a.x + c.y, 0.f), w, acc[0][1]);
            acc[1][0] = fmaf(fmaxf(a.y + c.x, 0.f), w, acc[1][0]);
            acc[1][1] = fmaf(fmaxf(a.y + c.y, 0.f), w, acc[1][1]);
        }
        __syncthreads();
    }

    const float bsv = bs2[0];
    #pragma unroll
    for (int di = 0; di < 2; ++di) {
        #pragma unroll
        for (int dj = 0; dj < 2; ++dj) {
            const int i = i0 + ty * 2 + di;
            const int j = j0 + tx * 2 + dj;
            if (i < j) {
                const float sg = 1.f / (1.f + __expf(-(acc[di][dj] + bsv)));
                S[i * 512 + j] = sg;
                S[j * 512 + i] = sg;
            } else if (i == j) {
                S[i * 512 + i] = 0.f;
            }
        }
    }
}

extern "C" void kernel_launch(void* const* d_in, const int* in_sizes, int n_in,
                              void* d_out, int out_size, void* d_ws, size_t ws_size,
                              hipStream_t stream)
{
    const float* x   = (const float*)d_in[0];
    const float* W1  = (const float*)d_in[1];
    const float* b1  = (const float*)d_in[2];
    const float* g   = (const float*)d_in[3];
    const float* be  = (const float*)d_in[4];
    const float* mu  = (const float*)d_in[5];
    const float* va  = (const float*)d_in[6];
    const float* W2  = (const float*)d_in[7];
    const float* b2  = (const float*)d_in[8];
    const float* W3  = (const float*)d_in[9];
    const float* b3  = (const float*)d_in[10];
    const float* Wa  = (const float*)d_in[11];
    const float* Wb  = (const float*)d_in[12];
    const float* bs1 = (const float*)d_in[13];
    const float* ws2 = (const float*)d_in[14];
    const float* bs2 = (const float*)d_in[15];

    float* out = (float*)d_out;
    float* ws  = (float*)d_ws;
    float* h   = ws;                          // 512*512
    float* h2  = h + 512 * 512;               // 512*256
    float* A   = h2 + 512 * 256;              // 512*512
    float* C   = A + 512 * 512;               // 512*512

    fused3_gemm<<<dim3(8, 16, 3), 256, 0, stream>>>(x, W1, b1, g, be, mu, va,
                                                    Wa, bs1, Wb, h, A, C);
    gemm_h2_kernel<<<dim3(4, 16), 256, 0, stream>>>(h, W2, b2, h2);
    head_kernel<<<128, 256, 0, stream>>>(h2, W3, b3, out);
    sim_kernel<<<136, 256, 0, stream>>>(A, C, ws2, bs2, out + 10240);
}

// Round 3
// 142.279 us; speedup vs baseline: 1.0645x; 1.0645x over previous
//
#include <hip/hip_runtime.h>
#include <math.h>

#define BN_EPS 1e-5f

// ---------------------------------------------------------------------------
// Shared GEMM body: out[m][n] = epilogue( sum_k X[m][k] * W[n][k] )
// X: [M,K] row-major, W: [N,K] row-major (i.e. computes X @ W^T).
// Tile: 32 (m) x 64 (n), k-chunk 32, 256 threads, 2x4 outputs/thread.
// mode: 0 = bias+BN+relu, 1 = bias+relu, 2 = bias only, 3 = none
// ---------------------------------------------------------------------------
__device__ __forceinline__ void gemm_body(
    const float* __restrict__ X, const float* __restrict__ W,
    const float* __restrict__ bias,
    const float* __restrict__ bn_g, const float* __restrict__ bn_b,
    const float* __restrict__ bn_m, const float* __restrict__ bn_v,
    float* __restrict__ out, int K, int ldo, int mode,
    float (*As)[36], float (*Bs)[68])
{
    const int t  = threadIdx.x;
    const int m0 = blockIdx.y * 32;
    const int n0 = blockIdx.x * 64;
    const int tx = t & 15;          // n quad index (0..15) -> n = n0 + 4*tx
    const int ty = t >> 4;          // m pair index (0..15) -> m = m0 + 2*ty
    const int lrow = t >> 3;        // staging row 0..31
    const int lk4  = (t & 7) << 2;  // staging k offset 0,4,...,28

    float acc[2][4];
    #pragma unroll
    for (int i = 0; i < 2; ++i)
        #pragma unroll
        for (int j = 0; j < 4; ++j) acc[i][j] = 0.f;

    for (int kc = 0; kc < K; kc += 32) {
        const float4 av = *(const float4*)&X[(m0 + lrow) * K + kc + lk4];
        const float4 bv0 = *(const float4*)&W[(n0 + lrow) * K + kc + lk4];
        const float4 bv1 = *(const float4*)&W[(n0 + lrow + 32) * K + kc + lk4];

        As[lk4 + 0][lrow] = av.x;
        As[lk4 + 1][lrow] = av.y;
        As[lk4 + 2][lrow] = av.z;
        As[lk4 + 3][lrow] = av.w;
        Bs[lk4 + 0][lrow] = bv0.x;
        Bs[lk4 + 1][lrow] = bv0.y;
        Bs[lk4 + 2][lrow] = bv0.z;
        Bs[lk4 + 3][lrow] = bv0.w;
        Bs[lk4 + 0][lrow + 32] = bv1.x;
        Bs[lk4 + 1][lrow + 32] = bv1.y;
        Bs[lk4 + 2][lrow + 32] = bv1.z;
        Bs[lk4 + 3][lrow + 32] = bv1.w;
        __syncthreads();

        #pragma unroll
        for (int k = 0; k < 32; ++k) {
            const float2 a = *(const float2*)&As[k][ty * 2];
            const float4 b = *(const float4*)&Bs[k][tx * 4];
            acc[0][0] = fmaf(a.x, b.x, acc[0][0]);
            acc[0][1] = fmaf(a.x, b.y, acc[0][1]);
            acc[0][2] = fmaf(a.x, b.z, acc[0][2]);
            acc[0][3] = fmaf(a.x, b.w, acc[0][3]);
            acc[1][0] = fmaf(a.y, b.x, acc[1][0]);
            acc[1][1] = fmaf(a.y, b.y, acc[1][1]);
            acc[1][2] = fmaf(a.y, b.z, acc[1][2]);
            acc[1][3] = fmaf(a.y, b.w, acc[1][3]);
        }
        __syncthreads();
    }

    const int n = n0 + tx * 4;
    #pragma unroll
    for (int i = 0; i < 2; ++i) {
        const int m = m0 + ty * 2 + i;
        float v[4];
        #pragma unroll
        for (int j = 0; j < 4; ++j) v[j] = acc[i][j];
        if (mode == 0) {
            #pragma unroll
            for (int j = 0; j < 4; ++j) {
                float z = v[j] + bias[n + j];
                z = bn_g[n + j] * (z - bn_m[n + j]) * rsqrtf(bn_v[n + j] + BN_EPS) + bn_b[n + j];
                v[j] = fmaxf(z, 0.f);
            }
        } else if (mode == 1) {
            #pragma unroll
            for (int j = 0; j < 4; ++j) v[j] = fmaxf(v[j] + bias[n + j], 0.f);
        } else if (mode == 2) {
            #pragma unroll
            for (int j = 0; j < 4; ++j) v[j] = v[j] + bias[n + j];
        }
        float4 o = make_float4(v[0], v[1], v[2], v[3]);
        *(float4*)&out[m * ldo + n] = o;
    }
}

// One launch computes h (BN+relu), A (=x@Ws1_a^T + bs1) and C (=x@Ws1_b^T)
// selected by blockIdx.z. All share M=512, N=512, K=256, X=x.
__global__ __launch_bounds__(256) void fused3_gemm(
    const float* __restrict__ x,
    const float* __restrict__ W1, const float* __restrict__ b1,
    const float* __restrict__ g, const float* __restrict__ be,
    const float* __restrict__ mu, const float* __restrict__ va,
    const float* __restrict__ Wa, const float* __restrict__ bs1,
    const float* __restrict__ Wb,
    float* __restrict__ h, float* __restrict__ A, float* __restrict__ C)
{
    __shared__ float As[32][36];
    __shared__ float Bs[32][68];
    const int z = blockIdx.z;
    if (z == 0)
        gemm_body(x, W1, b1, g, be, mu, va, h, 256, 512, 0, As, Bs);
    else if (z == 1)
        gemm_body(x, Wa, bs1, nullptr, nullptr, nullptr, nullptr, A, 256, 512, 2, As, Bs);
    else
        gemm_body(x, Wb, nullptr, nullptr, nullptr, nullptr, nullptr, C, 256, 512, 3, As, Bs);
}

// h2 = relu(h @ W2^T + b2), M=512, N=256, K=512
__global__ __launch_bounds__(256) void gemm_h2_kernel(
    const float* __restrict__ h, const float* __restrict__ W2,
    const float* __restrict__ b2, float* __restrict__ h2)
{
    __shared__ float As[32][36];
    __shared__ float Bs[32][68];
    gemm_body(h, W2, b2, nullptr, nullptr, nullptr, nullptr, h2, 512, 256, 1, As, Bs);
}

// scores = h2 @ W3^T + b3 ; softmax -> probs. One wave per row.
__global__ __launch_bounds__(256) void head_kernel(
    const float* __restrict__ h2, const float* __restrict__ W3,
    const float* __restrict__ b3, float* __restrict__ out)
{
    const int t = threadIdx.x;
    const int lane = t & 63;
    const int r = blockIdx.x * 4 + (t >> 6);

    float p[10];
    #pragma unroll
    for (int q = 0; q < 10; ++q) p[q] = 0.f;

    #pragma unroll
    for (int kk = 0; kk < 4; ++kk) {
        const int k = lane + kk * 64;
        const float hv = h2[r * 256 + k];
        #pragma unroll
        for (int q = 0; q < 10; ++q)
            p[q] = fmaf(hv, W3[q * 256 + k], p[q]);
    }
    #pragma unroll
    for (int q = 0; q < 10; ++q) {
        #pragma unroll
        for (int off = 32; off > 0; off >>= 1)
            p[q] += __shfl_down(p[q], off);
    }
    if (lane == 0) {
        float s[10], m = -1e30f;
        #pragma unroll
        for (int q = 0; q < 10; ++q) { s[q] = p[q] + b3[q]; m = fmaxf(m, s[q]); }
        float e[10], sum = 0.f;
        #pragma unroll
        for (int q = 0; q < 10; ++q) { e[q] = __expf(s[q] - m); sum += e[q]; }
        const float inv = 1.f / sum;
        #pragma unroll
        for (int q = 0; q < 10; ++q) {
            out[r * 10 + q] = e[q] * inv;          // pattern_probs
            out[5120 + r * 10 + q] = s[q];         // pattern_scores
        }
    }
}

// similarities: for i<j, sigmoid( sum_k relu(A[i,k]+C[j,k]) * ws2[k] + bs2 )
// 512 threads/block: wave-group 0 does k in [0,256), group 1 k in [256,512).
// Each group: 32x32 pair tile, 2x2 per thread. Partials combined via LDS.
// 2 waves/SIMD for latency hiding; per-wave serial k-chain halved.
__global__ __launch_bounds__(512) void sim_kernel(
    const float* __restrict__ A, const float* __restrict__ C,
    const float* __restrict__ ws2, const float* __restrict__ bs2,
    float* __restrict__ S)
{
    __shared__ float As[2][32][36];
    __shared__ float Cs[2][32][36];
    __shared__ float wsh[512];
    __shared__ float Ps[32][33];

    const int t  = threadIdx.x;
    const int g  = t >> 8;          // k-group 0/1
    const int tl = t & 255;         // lane within group
    const int b  = blockIdx.x;
    int jt = 0;
    while ((jt + 1) * (jt + 2) / 2 <= b) ++jt;
    const int it = b - jt * (jt + 1) / 2;
    const int i0 = it * 32, j0 = jt * 32;

    wsh[t] = ws2[t];

    const int tx = tl & 15, ty = tl >> 4;
    const int lrow = tl >> 3, lk4 = (tl & 7) << 2;
    const int kbase = g << 8;       // 0 or 256

    float acc[2][2] = {{0.f, 0.f}, {0.f, 0.f}};

    for (int kc = 0; kc < 256; kc += 32) {
        const int kk = kbase + kc;
        const float4 av = *(const float4*)&A[(i0 + lrow) * 512 + kk + lk4];
        const float4 cv = *(const float4*)&C[(j0 + lrow) * 512 + kk + lk4];
        As[g][lk4 + 0][lrow] = av.x;
        As[g][lk4 + 1][lrow] = av.y;
        As[g][lk4 + 2][lrow] = av.z;
        As[g][lk4 + 3][lrow] = av.w;
        Cs[g][lk4 + 0][lrow] = cv.x;
        Cs[g][lk4 + 1][lrow] = cv.y;
        Cs[g][lk4 + 2][lrow] = cv.z;
        Cs[g][lk4 + 3][lrow] = cv.w;
        __syncthreads();

        #pragma unroll
        for (int k = 0; k < 32; ++k) {
            const float2 a = *(const float2*)&As[g][k][ty * 2];
            const float2 c = *(const float2*)&Cs[g][k][tx * 2];
            const float w = wsh[kk + k];
            acc[0][0] = fmaf(fmaxf(a.x + c.x, 0.f), w, acc[0][0]);
            acc[0][1] = fmaf(fmaxf(a.x + c.y, 0.f), w, acc[0][1]);
            acc[1][0] = fmaf(fmaxf(a.y + c.x, 0.f), w, acc[1][0]);
            acc[1][1] = fmaf(fmaxf(a.y + c.y, 0.f), w, acc[1][1]);
        }
        __syncthreads();
    }

    if (g == 1) {
        Ps[ty * 2 + 0][tx * 2 + 0] = acc[0][0];
        Ps[ty * 2 + 0][tx * 2 + 1] = acc[0][1];
        Ps[ty * 2 + 1][tx * 2 + 0] = acc[1][0];
        Ps[ty * 2 + 1][tx * 2 + 1] = acc[1][1];
    }
    __syncthreads();

    if (g == 0) {
        const float bsv = bs2[0];
        #pragma unroll
        for (int di = 0; di < 2; ++di) {
            #pragma unroll
            for (int dj = 0; dj < 2; ++dj) {
                const int i = i0 + ty * 2 + di;
                const int j = j0 + tx * 2 + dj;
                const float v = acc[di][dj] + Ps[ty * 2 + di][tx * 2 + dj];
                if (i < j) {
                    const float sg = 1.f / (1.f + __expf(-(v + bsv)));
                    S[i * 512 + j] = sg;
                    S[j * 512 + i] = sg;
                } else if (i == j) {
                    S[i * 512 + i] = 0.f;
                }
            }
        }
    }
}

extern "C" void kernel_launch(void* const* d_in, const int* in_sizes, int n_in,
                              void* d_out, int out_size, void* d_ws, size_t ws_size,
                              hipStream_t stream)
{
    const float* x   = (const float*)d_in[0];
    const float* W1  = (const float*)d_in[1];
    const float* b1  = (const float*)d_in[2];
    const float* g   = (const float*)d_in[3];
    const float* be  = (const float*)d_in[4];
    const float* mu  = (const float*)d_in[5];
    const float* va  = (const float*)d_in[6];
    const float* W2  = (const float*)d_in[7];
    const float* b2  = (const float*)d_in[8];
    const float* W3  = (const float*)d_in[9];
    const float* b3  = (const float*)d_in[10];
    const float* Wa  = (const float*)d_in[11];
    const float* Wb  = (const float*)d_in[12];
    const float* bs1 = (const float*)d_in[13];
    const float* ws2 = (const float*)d_in[14];
    const float* bs2 = (const float*)d_in[15];

    float* out = (float*)d_out;
    float* ws  = (float*)d_ws;
    float* h   = ws;                          // 512*512
    float* h2  = h + 512 * 512;               // 512*256
    float* A   = h2 + 512 * 256;              // 512*512
    float* C   = A + 512 * 512;               // 512*512

    fused3_gemm<<<dim3(8, 16, 3), 256, 0, stream>>>(x, W1, b1, g, be, mu, va,
                                                    Wa, bs1, Wb, h, A, C);
    gemm_h2_kernel<<<dim3(4, 16), 256, 0, stream>>>(h, W2, b2, h2);
    head_kernel<<<128, 256, 0, stream>>>(h2, W3, b3, out);
    sim_kernel<<<136, 512, 0, stream>>>(A, C, ws2, bs2, out + 10240);
}

// Round 5
// 125.878 us; speedup vs baseline: 1.2032x; 1.1303x over previous
//
#include <hip/hip_runtime.h>
#include <math.h>

#define BN_EPS 1e-5f

typedef _Float16 half2v __attribute__((ext_vector_type(2)));

__device__ __forceinline__ float fdot2(half2v a, half2v b, float c) {
    return __builtin_amdgcn_fdot2(a, b, c, false);
}

// ---------------------------------------------------------------------------
// GEMM core: acc[2][4] += sum_k X[m][k] * W[n][k]; X:[M,K], W:[N,K] row-major.
// Tile 32(m) x 64(n), k-chunk 32, 256 threads (t), 2x4 outputs/thread.
// ---------------------------------------------------------------------------
__device__ __forceinline__ void gemm_core(
    const float* __restrict__ X, const float* __restrict__ W,
    int K, int ld, int m0, int n0, int t,
    float (*As)[36], float (*Bs)[68], float acc[2][4])
{
    const int tx = t & 15;
    const int ty = t >> 4;
    const int lrow = t >> 3;
    const int lk4  = (t & 7) << 2;

    for (int kc = 0; kc < K; kc += 32) {
        const float4 av  = *(const float4*)&X[(m0 + lrow) * ld + kc + lk4];
        const float4 bv0 = *(const float4*)&W[(n0 + lrow) * ld + kc + lk4];
        const float4 bv1 = *(const float4*)&W[(n0 + lrow + 32) * ld + kc + lk4];

        As[lk4 + 0][lrow] = av.x;
        As[lk4 + 1][lrow] = av.y;
        As[lk4 + 2][lrow] = av.z;
        As[lk4 + 3][lrow] = av.w;
        Bs[lk4 + 0][lrow] = bv0.x;
        Bs[lk4 + 1][lrow] = bv0.y;
        Bs[lk4 + 2][lrow] = bv0.z;
        Bs[lk4 + 3][lrow] = bv0.w;
        Bs[lk4 + 0][lrow + 32] = bv1.x;
        Bs[lk4 + 1][lrow + 32] = bv1.y;
        Bs[lk4 + 2][lrow + 32] = bv1.z;
        Bs[lk4 + 3][lrow + 32] = bv1.w;
        __syncthreads();

        #pragma unroll
        for (int k = 0; k < 32; ++k) {
            const float2 a = *(const float2*)&As[k][ty * 2];
            const float4 b = *(const float4*)&Bs[k][tx * 4];
            acc[0][0] = fmaf(a.x, b.x, acc[0][0]);
            acc[0][1] = fmaf(a.x, b.y, acc[0][1]);
            acc[0][2] = fmaf(a.x, b.z, acc[0][2]);
            acc[0][3] = fmaf(a.x, b.w, acc[0][3]);
            acc[1][0] = fmaf(a.y, b.x, acc[1][0]);
            acc[1][1] = fmaf(a.y, b.y, acc[1][1]);
            acc[1][2] = fmaf(a.y, b.z, acc[1][2]);
            acc[1][3] = fmaf(a.y, b.w, acc[1][3]);
        }
        __syncthreads();
    }
}

// z=0: h = relu(BN(x@W1^T+b1)) fp32; z=1: A16 = f16(x@Wa^T+bs1); z=2: C16 = f16(x@Wb^T)
__global__ __launch_bounds__(256) void fused3_gemm(
    const float* __restrict__ x,
    const float* __restrict__ W1, const float* __restrict__ b1,
    const float* __restrict__ g, const float* __restrict__ be,
    const float* __restrict__ mu, const float* __restrict__ va,
    const float* __restrict__ Wa, const float* __restrict__ bs1,
    const float* __restrict__ Wb,
    float* __restrict__ h, _Float16* __restrict__ A16, _Float16* __restrict__ C16)
{
    __shared__ float As[32][36];
    __shared__ float Bs[32][68];
    const int t = threadIdx.x;
    const int m0 = blockIdx.y * 32;
    const int n0 = blockIdx.x * 64;
    const int z = blockIdx.z;
    const int tx = t & 15, ty = t >> 4;

    float acc[2][4] = {};
    const float* W = (z == 0) ? W1 : (z == 1 ? Wa : Wb);
    gemm_core(x, W, 256, 256, m0, n0, t, As, Bs, acc);

    const int n = n0 + tx * 4;
    #pragma unroll
    for (int i = 0; i < 2; ++i) {
        const int m = m0 + ty * 2 + i;
        if (z == 0) {
            float v[4];
            #pragma unroll
            for (int j = 0; j < 4; ++j) {
                float zz = acc[i][j] + b1[n + j];
                zz = g[n + j] * (zz - mu[n + j]) * rsqrtf(va[n + j] + BN_EPS) + be[n + j];
                v[j] = fmaxf(zz, 0.f);
            }
            *(float4*)&h[m * 512 + n] = make_float4(v[0], v[1], v[2], v[3]);
        } else if (z == 1) {
            half2v p0, p1;
            p0.x = (_Float16)(acc[i][0] + bs1[n + 0]);
            p0.y = (_Float16)(acc[i][1] + bs1[n + 1]);
            p1.x = (_Float16)(acc[i][2] + bs1[n + 2]);
            p1.y = (_Float16)(acc[i][3] + bs1[n + 3]);
            *(half2v*)&A16[m * 512 + n] = p0;
            *(half2v*)&A16[m * 512 + n + 2] = p1;
        } else {
            half2v p0, p1;
            p0.x = (_Float16)acc[i][0];
            p0.y = (_Float16)acc[i][1];
            p1.x = (_Float16)acc[i][2];
            p1.y = (_Float16)acc[i][3];
            *(half2v*)&C16[m * 512 + n] = p0;
            *(half2v*)&C16[m * 512 + n + 2] = p1;
        }
    }
}

// h2 = relu(h @ W2^T + b2), M=512, N=256, K=512. 512 thr: 2 k-groups of 256.
__global__ __launch_bounds__(512) void gemm_h2_kernel(
    const float* __restrict__ h, const float* __restrict__ W2,
    const float* __restrict__ b2, float* __restrict__ h2o)
{
    __shared__ float As[2][32][36];
    __shared__ float Bs[2][32][68];
    __shared__ float Ps[32][68];
    const int t = threadIdx.x;
    const int gk = t >> 8;
    const int tl = t & 255;
    const int m0 = blockIdx.y * 32;
    const int n0 = blockIdx.x * 64;
    const int tx = tl & 15, ty = tl >> 4;
    const int lrow = tl >> 3, lk4 = (tl & 7) << 2;
    const int kb = gk << 8;

    float acc[2][4] = {};
    for (int kc = 0; kc < 256; kc += 32) {
        const int kk = kb + kc;
        const float4 av  = *(const float4*)&h[(m0 + lrow) * 512 + kk + lk4];
        const float4 bv0 = *(const float4*)&W2[(n0 + lrow) * 512 + kk + lk4];
        const float4 bv1 = *(const float4*)&W2[(n0 + lrow + 32) * 512 + kk + lk4];
        As[gk][lk4 + 0][lrow] = av.x;
        As[gk][lk4 + 1][lrow] = av.y;
        As[gk][lk4 + 2][lrow] = av.z;
        As[gk][lk4 + 3][lrow] = av.w;
        Bs[gk][lk4 + 0][lrow] = bv0.x;
        Bs[gk][lk4 + 1][lrow] = bv0.y;
        Bs[gk][lk4 + 2][lrow] = bv0.z;
        Bs[gk][lk4 + 3][lrow] = bv0.w;
        Bs[gk][lk4 + 0][lrow + 32] = bv1.x;
        Bs[gk][lk4 + 1][lrow + 32] = bv1.y;
        Bs[gk][lk4 + 2][lrow + 32] = bv1.z;
        Bs[gk][lk4 + 3][lrow + 32] = bv1.w;
        __syncthreads();
        #pragma unroll
        for (int k = 0; k < 32; ++k) {
            const float2 a = *(const float2*)&As[gk][k][ty * 2];
            const float4 b = *(const float4*)&Bs[gk][k][tx * 4];
            acc[0][0] = fmaf(a.x, b.x, acc[0][0]);
            acc[0][1] = fmaf(a.x, b.y, acc[0][1]);
            acc[0][2] = fmaf(a.x, b.z, acc[0][2]);
            acc[0][3] = fmaf(a.x, b.w, acc[0][3]);
            acc[1][0] = fmaf(a.y, b.x, acc[1][0]);
            acc[1][1] = fmaf(a.y, b.y, acc[1][1]);
            acc[1][2] = fmaf(a.y, b.z, acc[1][2]);
            acc[1][3] = fmaf(a.y, b.w, acc[1][3]);
        }
        __syncthreads();
    }

    if (gk == 1) {
        #pragma unroll
        for (int i = 0; i < 2; ++i)
            #pragma unroll
            for (int j = 0; j < 4; ++j)
                Ps[ty * 2 + i][tx * 4 + j] = acc[i][j];
    }
    __syncthreads();
    if (gk == 0) {
        const int n = n0 + tx * 4;
        #pragma unroll
        for (int i = 0; i < 2; ++i) {
            const int m = m0 + ty * 2 + i;
            float4 o;
            o.x = fmaxf(acc[i][0] + Ps[ty * 2 + i][tx * 4 + 0] + b2[n + 0], 0.f);
            o.y = fmaxf(acc[i][1] + Ps[ty * 2 + i][tx * 4 + 1] + b2[n + 1], 0.f);
            o.z = fmaxf(acc[i][2] + Ps[ty * 2 + i][tx * 4 + 2] + b2[n + 2], 0.f);
            o.w = fmaxf(acc[i][3] + Ps[ty * 2 + i][tx * 4 + 3] + b2[n + 3], 0.f);
            *(float4*)&h2o[m * 256 + n] = o;
        }
    }
}

// scores = h2 @ W3^T + b3 ; softmax -> probs. One wave per row.
__global__ __launch_bounds__(256) void head_kernel(
    const float* __restrict__ h2, const float* __restrict__ W3,
    const float* __restrict__ b3, float* __restrict__ out)
{
    const int t = threadIdx.x;
    const int lane = t & 63;
    const int r = blockIdx.x * 4 + (t >> 6);

    float p[10];
    #pragma unroll
    for (int q = 0; q < 10; ++q) p[q] = 0.f;

    #pragma unroll
    for (int kk = 0; kk < 4; ++kk) {
        const int k = lane + kk * 64;
        const float hv = h2[r * 256 + k];
        #pragma unroll
        for (int q = 0; q < 10; ++q)
            p[q] = fmaf(hv, W3[q * 256 + k], p[q]);
    }
    #pragma unroll
    for (int q = 0; q < 10; ++q) {
        #pragma unroll
        for (int off = 32; off > 0; off >>= 1)
            p[q] += __shfl_down(p[q], off);
    }
    if (lane == 0) {
        float s[10], m = -1e30f;
        #pragma unroll
        for (int q = 0; q < 10; ++q) { s[q] = p[q] + b3[q]; m = fmaxf(m, s[q]); }
        float e[10], sum = 0.f;
        #pragma unroll
        for (int q = 0; q < 10; ++q) { e[q] = __expf(s[q] - m); sum += e[q]; }
        const float inv = 1.f / sum;
        #pragma unroll
        for (int q = 0; q < 10; ++q) {
            out[r * 10 + q] = e[q] * inv;          // pattern_probs
            out[5120 + r * 10 + q] = s[q];         // pattern_scores
        }
    }
}

// similarities, full grid 16x16: block (bx,by) -> out rows r0=by*32, cols q0=bx*32.
// value(r,q) = sigmoid( sum_k relu(A[min]+C[max]) * w + bs2 ), diag 0.
// Upper (r0<q0): Rs=A-rows, Qs=C-cols. Lower: Rs=C-rows, Qs=A-cols (commutative add).
// 512 thr: k-group g in {0,1} covers k in [g*256,(g+1)*256). Packed f16 + dot2.
#define SIMS 260  // LDS row stride in halfs: 520 B -> 8B aligned
__global__ __launch_bounds__(512) void sim_kernel(
    const _Float16* __restrict__ A16, const _Float16* __restrict__ C16,
    const float* __restrict__ ws2, const float* __restrict__ bs2,
    float* __restrict__ S)
{
    __shared__ _Float16 Rs[2][32][SIMS];
    __shared__ _Float16 Qs[2][32][SIMS];
    __shared__ half2v wsh[256];
    __shared__ float Ps[32][33];
    __shared__ float Tt[32][33];

    const int t  = threadIdx.x;
    const int gk = t >> 8;
    const int tl = t & 255;
    const int r0 = blockIdx.y * 32;
    const int q0 = blockIdx.x * 32;
    const bool diag = (r0 == q0);
    const _Float16* RsSrc = (r0 <= q0) ? A16 : C16;
    const _Float16* QsSrc = (r0 <= q0) ? C16 : A16;
    const int kbase = gk << 8;

    if (t < 256) {
        half2v w;
        w.x = (_Float16)ws2[2 * t];
        w.y = (_Float16)ws2[2 * t + 1];
        wsh[t] = w;
    }

    #pragma unroll
    for (int i = 0; i < 4; ++i) {
        const int idx = tl + i * 256;       // 0..1023
        const int row = idx >> 5;           // 0..31
        const int c8  = idx & 31;           // 16B chunk in 512B k-strip
        const float4 vr = *(const float4*)&RsSrc[(r0 + row) * 512 + kbase + c8 * 8];
        const float4 vq = *(const float4*)&QsSrc[(q0 + row) * 512 + kbase + c8 * 8];
        char* dr = (char*)&Rs[gk][row][0] + c8 * 16;
        ((float2*)dr)[0] = make_float2(vr.x, vr.y);
        ((float2*)dr)[1] = make_float2(vr.z, vr.w);
        char* dq = (char*)&Qs[gk][row][0] + c8 * 16;
        ((float2*)dq)[0] = make_float2(vq.x, vq.y);
        ((float2*)dq)[1] = make_float2(vq.z, vq.w);
    }
    __syncthreads();

    const int tx = tl & 15, ty = tl >> 4;
    const half2v* rp0 = (const half2v*)&Rs[gk][ty * 2][0];
    const half2v* rp1 = (const half2v*)&Rs[gk][ty * 2 + 1][0];
    const half2v* qp0 = (const half2v*)&Qs[gk][tx * 2][0];
    const half2v* qp1 = (const half2v*)&Qs[gk][tx * 2 + 1][0];
    const half2v* wp  = &wsh[gk * 128];
    const half2v z2 = {(_Float16)0, (_Float16)0};

    float a00 = 0.f, a01 = 0.f, a10 = 0.f, a11 = 0.f;
    #pragma unroll 16
    for (int k2 = 0; k2 < 128; ++k2) {
        const half2v r0v = rp0[k2], r1v = rp1[k2];
        const half2v q0v = qp0[k2], q1v = qp1[k2];
        const half2v w2 = wp[k2];
        a00 = fdot2(__builtin_elementwise_max(r0v + q0v, z2), w2, a00);
        a01 = fdot2(__builtin_elementwise_max(r0v + q1v, z2), w2, a01);
        a10 = fdot2(__builtin_elementwise_max(r1v + q0v, z2), w2, a10);
        a11 = fdot2(__builtin_elementwise_max(r1v + q1v, z2), w2, a11);
    }

    if (gk == 1) {
        Ps[ty * 2 + 0][tx * 2 + 0] = a00;
        Ps[ty * 2 + 0][tx * 2 + 1] = a01;
        Ps[ty * 2 + 1][tx * 2 + 0] = a10;
        Ps[ty * 2 + 1][tx * 2 + 1] = a11;
    }
    __syncthreads();

    if (gk == 0) {
        const float bsv = bs2[0];
        float v[2][2];
        v[0][0] = a00 + Ps[ty * 2 + 0][tx * 2 + 0];
        v[0][1] = a01 + Ps[ty * 2 + 0][tx * 2 + 1];
        v[1][0] = a10 + Ps[ty * 2 + 1][tx * 2 + 0];
        v[1][1] = a11 + Ps[ty * 2 + 1][tx * 2 + 1];
        #pragma unroll
        for (int di = 0; di < 2; ++di)
            #pragma unroll
            for (int dj = 0; dj < 2; ++dj)
                v[di][dj] = 1.f / (1.f + __expf(-(v[di][dj] + bsv)));
        if (!diag) {
            #pragma unroll
            for (int di = 0; di < 2; ++di)
                *(float2*)&S[(r0 + ty * 2 + di) * 512 + q0 + tx * 2] =
                    make_float2(v[di][0], v[di][1]);
        } else {
            #pragma unroll
            for (int di = 0; di < 2; ++di)
                #pragma unroll
                for (int dj = 0; dj < 2; ++dj)
                    Tt[ty * 2 + di][tx * 2 + dj] = v[di][dj];
        }
    }
    if (diag) {
        __syncthreads();
        if (gk == 0) {
            #pragma unroll
            for (int di = 0; di < 2; ++di)
                #pragma unroll
                for (int dj = 0; dj < 2; ++dj) {
                    const int rl = ty * 2 + di, ql = tx * 2 + dj;
                    const float o = rl < ql ? Tt[rl][ql] : (rl > ql ? Tt[ql][rl] : 0.f);
                    S[(r0 + rl) * 512 + q0 + ql] = o;
                }
        }
    }
}

extern "C" void kernel_launch(void* const* d_in, const int* in_sizes, int n_in,
                              void* d_out, int out_size, void* d_ws, size_t ws_size,
                              hipStream_t stream)
{
    const float* x   = (const float*)d_in[0];
    const float* W1  = (const float*)d_in[1];
    const float* b1  = (const float*)d_in[2];
    const float* g   = (const float*)d_in[3];
    const float* be  = (const float*)d_in[4];
    const float* mu  = (const float*)d_in[5];
    const float* va  = (const float*)d_in[6];
    const float* W2  = (const float*)d_in[7];
    const float* b2  = (const float*)d_in[8];
    const float* W3  = (const float*)d_in[9];
    const float* b3  = (const float*)d_in[10];
    const float* Wa  = (const float*)d_in[11];
    const float* Wb  = (const float*)d_in[12];
    const float* bs1 = (const float*)d_in[13];
    const float* ws2 = (const float*)d_in[14];
    const float* bs2 = (const float*)d_in[15];

    float* out = (float*)d_out;
    float* ws  = (float*)d_ws;
    float* h   = ws;                               // 512*512 f32
    float* h2  = h + 512 * 512;                    // 512*256 f32
    _Float16* A16 = (_Float16*)(h2 + 512 * 256);   // 512*512 f16
    _Float16* C16 = A16 + 512 * 512;               // 512*512 f16

    fused3_gemm<<<dim3(8, 16, 3), 256, 0, stream>>>(x, W1, b1, g, be, mu, va,
                                                    Wa, bs1, Wb, h, A16, C16);
    gemm_h2_kernel<<<dim3(4, 16), 512, 0, stream>>>(h, W2, b2, h2);
    head_kernel<<<128, 256, 0, stream>>>(h2, W3, b3, out);
    sim_kernel<<<dim3(16, 16), 512, 0, stream>>>(A16, C16, ws2, bs2, out + 10240);
}

// Round 7
// 119.305 us; speedup vs baseline: 1.2695x; 1.0551x over previous
//
#include <hip/hip_runtime.h>
#include <math.h>

#define BN_EPS 1e-5f

typedef _Float16 half2v __attribute__((ext_vector_type(2)));
typedef _Float16 half4v __attribute__((ext_vector_type(4)));
typedef _Float16 half8v __attribute__((ext_vector_type(8)));

__device__ __forceinline__ float fdot2(half2v a, half2v b, float c) {
    return __builtin_amdgcn_fdot2(a, b, c, false);
}
__device__ __forceinline__ half2v cvt2(float a, float b) {
    return __builtin_bit_cast(half2v, __builtin_amdgcn_cvt_pkrtz(a, b));
}

// ---------------------------------------------------------------------------
// fused3: z=0: h16 = f16(relu(BN(x@W1^T+b1))); z=1: A16 = f16(x@Wa^T+bs1);
// z=2: C16 = f16(x@Wb^T).  M=512,N=512,K=256, X=x fp32, W fp32 -> f16 LDS.
// Tile 32(m) x 64(n), k-chunk 32 (16 k-pairs), 256 thr, 2x4 out/thread.
// LDS k2-major: As16[k2][row] (pairs k,k+1), dot2 inner loop.
// ---------------------------------------------------------------------------
__global__ __launch_bounds__(256) void fused3_gemm(
    const float* __restrict__ x,
    const float* __restrict__ W1, const float* __restrict__ b1,
    const float* __restrict__ g, const float* __restrict__ be,
    const float* __restrict__ mu, const float* __restrict__ va,
    const float* __restrict__ Wa, const float* __restrict__ bs1,
    const float* __restrict__ Wb,
    _Float16* __restrict__ h16, _Float16* __restrict__ A16,
    _Float16* __restrict__ C16)
{
    __shared__ half2v As16[16][36];   // stride 36*4B=144B (16B mult)
    __shared__ half2v Bs16[16][72];   // stride 72*4B=288B (16B mult)

    const int t  = threadIdx.x;
    const int m0 = blockIdx.y * 32;
    const int n0 = blockIdx.x * 64;
    const int z  = blockIdx.z;
    const int tx = t & 15, ty = t >> 4;
    const int lrow = t >> 3;          // 0..31
    const int lk4  = (t & 7) << 2;    // 0,4,...,28
    const int k2b  = lk4 >> 1;        // 0,2,...,14

    const float* __restrict__ W = (z == 0) ? W1 : (z == 1 ? Wa : Wb);

    float acc[2][4] = {};

    for (int kc = 0; kc < 256; kc += 32) {
        const float4 av  = *(const float4*)&x[(m0 + lrow) * 256 + kc + lk4];
        const float4 bv0 = *(const float4*)&W[(n0 + lrow) * 256 + kc + lk4];
        const float4 bv1 = *(const float4*)&W[(n0 + lrow + 32) * 256 + kc + lk4];

        As16[k2b + 0][lrow] = cvt2(av.x, av.y);
        As16[k2b + 1][lrow] = cvt2(av.z, av.w);
        Bs16[k2b + 0][lrow] = cvt2(bv0.x, bv0.y);
        Bs16[k2b + 1][lrow] = cvt2(bv0.z, bv0.w);
        Bs16[k2b + 0][lrow + 32] = cvt2(bv1.x, bv1.y);
        Bs16[k2b + 1][lrow + 32] = cvt2(bv1.z, bv1.w);
        __syncthreads();

        #pragma unroll
        for (int k2 = 0; k2 < 16; ++k2) {
            const half4v a4 = *(const half4v*)&As16[k2][ty * 2];
            const half8v b8 = *(const half8v*)&Bs16[k2][tx * 4];
            const half2v a0 = __builtin_shufflevector(a4, a4, 0, 1);
            const half2v a1 = __builtin_shufflevector(a4, a4, 2, 3);
            const half2v b0 = __builtin_shufflevector(b8, b8, 0, 1);
            const half2v b1h = __builtin_shufflevector(b8, b8, 2, 3);
            const half2v b2h = __builtin_shufflevector(b8, b8, 4, 5);
            const half2v b3h = __builtin_shufflevector(b8, b8, 6, 7);
            acc[0][0] = fdot2(a0, b0, acc[0][0]);
            acc[0][1] = fdot2(a0, b1h, acc[0][1]);
            acc[0][2] = fdot2(a0, b2h, acc[0][2]);
            acc[0][3] = fdot2(a0, b3h, acc[0][3]);
            acc[1][0] = fdot2(a1, b0, acc[1][0]);
            acc[1][1] = fdot2(a1, b1h, acc[1][1]);
            acc[1][2] = fdot2(a1, b2h, acc[1][2]);
            acc[1][3] = fdot2(a1, b3h, acc[1][3]);
        }
        __syncthreads();
    }

    const int n = n0 + tx * 4;
    #pragma unroll
    for (int i = 0; i < 2; ++i) {
        const int m = m0 + ty * 2 + i;
        half4v o;
        if (z == 0) {
            #pragma unroll
            for (int j = 0; j < 4; ++j) {
                float zz = acc[i][j] + b1[n + j];
                zz = g[n + j] * (zz - mu[n + j]) * rsqrtf(va[n + j] + BN_EPS) + be[n + j];
                o[j] = (_Float16)fmaxf(zz, 0.f);
            }
            *(half4v*)&h16[m * 512 + n] = o;
        } else if (z == 1) {
            #pragma unroll
            for (int j = 0; j < 4; ++j) o[j] = (_Float16)(acc[i][j] + bs1[n + j]);
            *(half4v*)&A16[m * 512 + n] = o;
        } else {
            #pragma unroll
            for (int j = 0; j < 4; ++j) o[j] = (_Float16)acc[i][j];
            *(half4v*)&C16[m * 512 + n] = o;
        }
    }
}

// ---------------------------------------------------------------------------
// h2 = relu(h16 @ W2^T + b2) fp32 out. M=512, N=256, K=512.
// 512 thr: k-groups of 256 k (128 k2 each), f16 dot2, LDS partial combine.
// ---------------------------------------------------------------------------
__global__ __launch_bounds__(512) void gemm_h2_kernel(
    const _Float16* __restrict__ h16, const float* __restrict__ W2,
    const float* __restrict__ b2, float* __restrict__ h2o)
{
    __shared__ half2v As16[2][16][36];
    __shared__ half2v Bs16[2][16][72];
    __shared__ float Ps[32][68];

    const int t  = threadIdx.x;
    const int gk = t >> 8;
    const int tl = t & 255;
    const int m0 = blockIdx.y * 32;
    const int n0 = blockIdx.x * 64;
    const int tx = tl & 15, ty = tl >> 4;
    const int kb = gk << 8;

    float acc[2][4] = {};

    for (int kc = 0; kc < 256; kc += 32) {
        const int kk = kb + kc;
        // A: h16 f16, 32 rows x 32k = 128 loads of 8 halfs; threads tl<128
        if (tl < 128) {
            const int arow = tl >> 2;        // 0..31
            const int ak8  = (tl & 3) << 3;  // 0,8,16,24
            const float4 av = *(const float4*)&h16[(m0 + arow) * 512 + kk + ak8];
            const half2v* ap = (const half2v*)&av;
            const int k2 = ak8 >> 1;
            As16[gk][k2 + 0][arow] = ap[0];
            As16[gk][k2 + 1][arow] = ap[1];
            As16[gk][k2 + 2][arow] = ap[2];
            As16[gk][k2 + 3][arow] = ap[3];
        }
        // B: W2 fp32 -> f16, 64 rows x 32k = 256 tasks of 8 floats
        {
            const int brow = tl >> 2;        // 0..63
            const int bk8  = (tl & 3) << 3;  // 0,8,16,24
            const float4 bv0 = *(const float4*)&W2[(n0 + brow) * 512 + kk + bk8];
            const float4 bv1 = *(const float4*)&W2[(n0 + brow) * 512 + kk + bk8 + 4];
            const int k2 = bk8 >> 1;
            Bs16[gk][k2 + 0][brow] = cvt2(bv0.x, bv0.y);
            Bs16[gk][k2 + 1][brow] = cvt2(bv0.z, bv0.w);
            Bs16[gk][k2 + 2][brow] = cvt2(bv1.x, bv1.y);
            Bs16[gk][k2 + 3][brow] = cvt2(bv1.z, bv1.w);
        }
        __syncthreads();

        #pragma unroll
        for (int k2 = 0; k2 < 16; ++k2) {
            const half4v a4 = *(const half4v*)&As16[gk][k2][ty * 2];
            const half8v b8 = *(const half8v*)&Bs16[gk][k2][tx * 4];
            const half2v a0 = __builtin_shufflevector(a4, a4, 0, 1);
            const half2v a1 = __builtin_shufflevector(a4, a4, 2, 3);
            const half2v b0 = __builtin_shufflevector(b8, b8, 0, 1);
            const half2v b1h = __builtin_shufflevector(b8, b8, 2, 3);
            const half2v b2h = __builtin_shufflevector(b8, b8, 4, 5);
            const half2v b3h = __builtin_shufflevector(b8, b8, 6, 7);
            acc[0][0] = fdot2(a0, b0, acc[0][0]);
            acc[0][1] = fdot2(a0, b1h, acc[0][1]);
            acc[0][2] = fdot2(a0, b2h, acc[0][2]);
            acc[0][3] = fdot2(a0, b3h, acc[0][3]);
            acc[1][0] = fdot2(a1, b0, acc[1][0]);
            acc[1][1] = fdot2(a1, b1h, acc[1][1]);
            acc[1][2] = fdot2(a1, b2h, acc[1][2]);
            acc[1][3] = fdot2(a1, b3h, acc[1][3]);
        }
        __syncthreads();
    }

    if (gk == 1) {
        #pragma unroll
        for (int i = 0; i < 2; ++i)
            #pragma unroll
            for (int j = 0; j < 4; ++j)
                Ps[ty * 2 + i][tx * 4 + j] = acc[i][j];
    }
    __syncthreads();
    if (gk == 0) {
        const int n = n0 + tx * 4;
        #pragma unroll
        for (int i = 0; i < 2; ++i) {
            const int m = m0 + ty * 2 + i;
            float4 o;
            o.x = fmaxf(acc[i][0] + Ps[ty * 2 + i][tx * 4 + 0] + b2[n + 0], 0.f);
            o.y = fmaxf(acc[i][1] + Ps[ty * 2 + i][tx * 4 + 1] + b2[n + 1], 0.f);
            o.z = fmaxf(acc[i][2] + Ps[ty * 2 + i][tx * 4 + 2] + b2[n + 2], 0.f);
            o.w = fmaxf(acc[i][3] + Ps[ty * 2 + i][tx * 4 + 3] + b2[n + 3], 0.f);
            *(float4*)&h2o[m * 256 + n] = o;
        }
    }
}

// scores = h2 @ W3^T + b3 ; softmax -> probs. One wave per row.
__global__ __launch_bounds__(256) void head_kernel(
    const float* __restrict__ h2, const float* __restrict__ W3,
    const float* __restrict__ b3, float* __restrict__ out)
{
    const int t = threadIdx.x;
    const int lane = t & 63;
    const int r = blockIdx.x * 4 + (t >> 6);

    float p[10];
    #pragma unroll
    for (int q = 0; q < 10; ++q) p[q] = 0.f;

    #pragma unroll
    for (int kk = 0; kk < 4; ++kk) {
        const int k = lane + kk * 64;
        const float hv = h2[r * 256 + k];
        #pragma unroll
        for (int q = 0; q < 10; ++q)
            p[q] = fmaf(hv, W3[q * 256 + k], p[q]);
    }
    #pragma unroll
    for (int q = 0; q < 10; ++q) {
        #pragma unroll
        for (int off = 32; off > 0; off >>= 1)
            p[q] += __shfl_down(p[q], off);
    }
    if (lane == 0) {
        float s[10], m = -1e30f;
        #pragma unroll
        for (int q = 0; q < 10; ++q) { s[q] = p[q] + b3[q]; m = fmaxf(m, s[q]); }
        float e[10], sum = 0.f;
        #pragma unroll
        for (int q = 0; q < 10; ++q) { e[q] = __expf(s[q] - m); sum += e[q]; }
        const float inv = 1.f / sum;
        #pragma unroll
        for (int q = 0; q < 10; ++q) {
            out[r * 10 + q] = e[q] * inv;          // pattern_probs
            out[5120 + r * 10 + q] = s[q];         // pattern_scores
        }
    }
}

// similarities, full grid 16x16 (unchanged — at its VALU floor).
#define SIMS 260
__global__ __launch_bounds__(512) void sim_kernel(
    const _Float16* __restrict__ A16, const _Float16* __restrict__ C16,
    const float* __restrict__ ws2, const float* __restrict__ bs2,
    float* __restrict__ S)
{
    __shared__ _Float16 Rs[2][32][SIMS];
    __shared__ _Float16 Qs[2][32][SIMS];
    __shared__ half2v wsh[256];
    __shared__ float Ps[32][33];
    __shared__ float Tt[32][33];

    const int t  = threadIdx.x;
    const int gk = t >> 8;
    const int tl = t & 255;
    const int r0 = blockIdx.y * 32;
    const int q0 = blockIdx.x * 32;
    const bool diag = (r0 == q0);
    const _Float16* RsSrc = (r0 <= q0) ? A16 : C16;
    const _Float16* QsSrc = (r0 <= q0) ? C16 : A16;
    const int kbase = gk << 8;

    if (t < 256) {
        half2v w;
        w.x = (_Float16)ws2[2 * t];
        w.y = (_Float16)ws2[2 * t + 1];
        wsh[t] = w;
    }

    #pragma unroll
    for (int i = 0; i < 4; ++i) {
        const int idx = tl + i * 256;
        const int row = idx >> 5;
        const int c8  = idx & 31;
        const float4 vr = *(const float4*)&RsSrc[(r0 + row) * 512 + kbase + c8 * 8];
        const float4 vq = *(const float4*)&QsSrc[(q0 + row) * 512 + kbase + c8 * 8];
        char* dr = (char*)&Rs[gk][row][0] + c8 * 16;
        ((float2*)dr)[0] = make_float2(vr.x, vr.y);
        ((float2*)dr)[1] = make_float2(vr.z, vr.w);
        char* dq = (char*)&Qs[gk][row][0] + c8 * 16;
        ((float2*)dq)[0] = make_float2(vq.x, vq.y);
        ((float2*)dq)[1] = make_float2(vq.z, vq.w);
    }
    __syncthreads();

    const int tx = tl & 15, ty = tl >> 4;
    const half2v* rp0 = (const half2v*)&Rs[gk][ty * 2][0];
    const half2v* rp1 = (const half2v*)&Rs[gk][ty * 2 + 1][0];
    const half2v* qp0 = (const half2v*)&Qs[gk][tx * 2][0];
    const half2v* qp1 = (const half2v*)&Qs[gk][tx * 2 + 1][0];
    const half2v* wp  = &wsh[gk * 128];
    const half2v z2 = {(_Float16)0, (_Float16)0};

    float a00 = 0.f, a01 = 0.f, a10 = 0.f, a11 = 0.f;
    #pragma unroll 16
    for (int k2 = 0; k2 < 128; ++k2) {
        const half2v r0v = rp0[k2], r1v = rp1[k2];
        const half2v q0v = qp0[k2], q1v = qp1[k2];
        const half2v w2 = wp[k2];
        a00 = fdot2(__builtin_elementwise_max(r0v + q0v, z2), w2, a00);
        a01 = fdot2(__builtin_elementwise_max(r0v + q1v, z2), w2, a01);
        a10 = fdot2(__builtin_elementwise_max(r1v + q0v, z2), w2, a10);
        a11 = fdot2(__builtin_elementwise_max(r1v + q1v, z2), w2, a11);
    }

    if (gk == 1) {
        Ps[ty * 2 + 0][tx * 2 + 0] = a00;
        Ps[ty * 2 + 0][tx * 2 + 1] = a01;
        Ps[ty * 2 + 1][tx * 2 + 0] = a10;
        Ps[ty * 2 + 1][tx * 2 + 1] = a11;
    }
    __syncthreads();

    if (gk == 0) {
        const float bsv = bs2[0];
        float v[2][2];
        v[0][0] = a00 + Ps[ty * 2 + 0][tx * 2 + 0];
        v[0][1] = a01 + Ps[ty * 2 + 0][tx * 2 + 1];
        v[1][0] = a10 + Ps[ty * 2 + 1][tx * 2 + 0];
        v[1][1] = a11 + Ps[ty * 2 + 1][tx * 2 + 1];
        #pragma unroll
        for (int di = 0; di < 2; ++di)
            #pragma unroll
            for (int dj = 0; dj < 2; ++dj)
                v[di][dj] = 1.f / (1.f + __expf(-(v[di][dj] + bsv)));
        if (!diag) {
            #pragma unroll
            for (int di = 0; di < 2; ++di)
                *(float2*)&S[(r0 + ty * 2 + di) * 512 + q0 + tx * 2] =
                    make_float2(v[di][0], v[di][1]);
        } else {
            #pragma unroll
            for (int di = 0; di < 2; ++di)
                #pragma unroll
                for (int dj = 0; dj < 2; ++dj)
                    Tt[ty * 2 + di][tx * 2 + dj] = v[di][dj];
        }
    }
    if (diag) {
        __syncthreads();
        if (gk == 0) {
            #pragma unroll
            for (int di = 0; di < 2; ++di)
                #pragma unroll
                for (int dj = 0; dj < 2; ++dj) {
                    const int rl = ty * 2 + di, ql = tx * 2 + dj;
                    const float o = rl < ql ? Tt[rl][ql] : (rl > ql ? Tt[ql][rl] : 0.f);
                    S[(r0 + rl) * 512 + q0 + ql] = o;
                }
        }
    }
}

extern "C" void kernel_launch(void* const* d_in, const int* in_sizes, int n_in,
                              void* d_out, int out_size, void* d_ws, size_t ws_size,
                              hipStream_t stream)
{
    const float* x   = (const float*)d_in[0];
    const float* W1  = (const float*)d_in[1];
    const float* b1  = (const float*)d_in[2];
    const float* g   = (const float*)d_in[3];
    const float* be  = (const float*)d_in[4];
    const float* mu  = (const float*)d_in[5];
    const float* va  = (const float*)d_in[6];
    const float* W2  = (const float*)d_in[7];
    const float* b2  = (const float*)d_in[8];
    const float* W3  = (const float*)d_in[9];
    const float* b3  = (const float*)d_in[10];
    const float* Wa  = (const float*)d_in[11];
    const float* Wb  = (const float*)d_in[12];
    const float* bs1 = (const float*)d_in[13];
    const float* ws2 = (const float*)d_in[14];
    const float* bs2 = (const float*)d_in[15];

    float* out = (float*)d_out;
    _Float16* h16 = (_Float16*)d_ws;               // 512*512 f16
    float* h2 = (float*)(h16 + 512 * 512);         // 512*256 f32
    _Float16* A16 = (_Float16*)(h2 + 512 * 256);   // 512*512 f16
    _Float16* C16 = A16 + 512 * 512;               // 512*512 f16

    fused3_gemm<<<dim3(8, 16, 3), 256, 0, stream>>>(x, W1, b1, g, be, mu, va,
                                                    Wa, bs1, Wb, h16, A16, C16);
    gemm_h2_kernel<<<dim3(4, 16), 512, 0, stream>>>(h16, W2, b2, h2);
    head_kernel<<<128, 256, 0, stream>>>(h2, W3, b3, out);
    sim_kernel<<<dim3(16, 16), 512, 0, stream>>>(A16, C16, ws2, bs2, out + 10240);
}

// Round 8
// 111.035 us; speedup vs baseline: 1.3641x; 1.0745x over previous
//
#include <hip/hip_runtime.h>
#include <math.h>

#define BN_EPS 1e-5f

typedef _Float16 half2v __attribute__((ext_vector_type(2)));
typedef _Float16 half4v __attribute__((ext_vector_type(4)));
typedef _Float16 half8v __attribute__((ext_vector_type(8)));
typedef __fp16 fp16x8 __attribute__((ext_vector_type(8)));
typedef float floatx4 __attribute__((ext_vector_type(4)));

__device__ __forceinline__ float fdot2(half2v a, half2v b, float c) {
    return __builtin_amdgcn_fdot2(a, b, c, false);
}
__device__ __forceinline__ half2v cvt2(float a, float b) {
    return __builtin_bit_cast(half2v, __builtin_amdgcn_cvt_pkrtz(a, b));
}
__device__ __forceinline__ floatx4 mfma16(half8v a, half8v b, floatx4 c) {
    return __builtin_amdgcn_mfma_f32_16x16x32_f16(
        __builtin_bit_cast(fp16x8, a), __builtin_bit_cast(fp16x8, b), c, 0, 0, 0);
}

// ---------------------------------------------------------------------------
// fused3 (MFMA): z=0: h16=f16(relu(BN(x@W1^T+b1))); z=1: A16=f16(x@Wa^T+bs1);
// z=2: C16=f16(x@Wb^T).  M=512,N=512,K=256.
// Tile 64m x 32n, full-K f16 LDS strips (pad +8 -> stride 528B, 132w==4 mod 32
// banks: b128 frag reads only 2-way conflicted = free). 256 thr = 4 waves in
// 2x2; wave = 32m x 16n = 2 mfma-tiles x 8 k-chunks of 16x16x32.
// A-frag: A[m=lane&15][k=quad*8+j]; B-frag: B[k=quad*8+j][n=lane&15]=W[n][k];
// C/D: row=quad*4+reg, col=lane&15 (guide-verified, dtype-independent).
// ---------------------------------------------------------------------------
__global__ __launch_bounds__(256) void fused3_mfma(
    const float* __restrict__ x,
    const float* __restrict__ W1, const float* __restrict__ b1,
    const float* __restrict__ g, const float* __restrict__ be,
    const float* __restrict__ mu, const float* __restrict__ va,
    const float* __restrict__ Wa, const float* __restrict__ bs1,
    const float* __restrict__ Wb,
    _Float16* __restrict__ h16, _Float16* __restrict__ A16,
    _Float16* __restrict__ C16)
{
    __shared__ _Float16 Xs[64][264];
    __shared__ _Float16 Ws[32][264];

    const int t  = threadIdx.x;
    const int n0 = blockIdx.x * 32;
    const int m0 = blockIdx.y * 64;
    const int z  = blockIdx.z;
    const float* __restrict__ Wp = (z == 0) ? W1 : (z == 1 ? Wa : Wb);

    // Stage X: 64 rows x 64 float4 = 4096 chunks (16/thread)
    #pragma unroll
    for (int i = 0; i < 16; ++i) {
        const int cidx = t + i * 256;
        const int row = cidx >> 6;
        const int c4  = cidx & 63;
        const float4 v = *(const float4*)&x[(m0 + row) * 256 + c4 * 4];
        *(half2v*)&Xs[row][c4 * 4 + 0] = cvt2(v.x, v.y);
        *(half2v*)&Xs[row][c4 * 4 + 2] = cvt2(v.z, v.w);
    }
    // Stage W: 32 rows x 64 float4 = 2048 chunks (8/thread)
    #pragma unroll
    for (int i = 0; i < 8; ++i) {
        const int cidx = t + i * 256;
        const int row = cidx >> 6;
        const int c4  = cidx & 63;
        const float4 v = *(const float4*)&Wp[(n0 + row) * 256 + c4 * 4];
        *(half2v*)&Ws[row][c4 * 4 + 0] = cvt2(v.x, v.y);
        *(half2v*)&Ws[row][c4 * 4 + 2] = cvt2(v.z, v.w);
    }
    __syncthreads();

    const int wave = t >> 6;
    const int lane = t & 63;
    const int wy = wave >> 1, wx = wave & 1;   // 2x2 wave grid over 64m x 32n
    const int lrow = lane & 15;
    const int quad = lane >> 4;
    const int kq = quad * 8;

    floatx4 acc[2] = {{0.f, 0.f, 0.f, 0.f}, {0.f, 0.f, 0.f, 0.f}};

    #pragma unroll
    for (int kc = 0; kc < 256; kc += 32) {
        const half8v a0 = *(const half8v*)&Xs[wy * 32 + lrow][kc + kq];
        const half8v a1 = *(const half8v*)&Xs[wy * 32 + 16 + lrow][kc + kq];
        const half8v b0 = *(const half8v*)&Ws[wx * 16 + lrow][kc + kq];
        acc[0] = mfma16(a0, b0, acc[0]);
        acc[1] = mfma16(a1, b0, acc[1]);
    }

    const int n = n0 + wx * 16 + lrow;
    float scale, off;
    if (z == 0) {
        const float s = g[n] * rsqrtf(va[n] + BN_EPS);
        scale = s;
        off = (b1[n] - mu[n]) * s + be[n];
    } else if (z == 1) {
        scale = 1.f;
        off = bs1[n];
    } else {
        scale = 1.f;
        off = 0.f;
    }
    _Float16* __restrict__ dst = (z == 0) ? h16 : (z == 1 ? A16 : C16);
    #pragma unroll
    for (int mi = 0; mi < 2; ++mi) {
        #pragma unroll
        for (int r = 0; r < 4; ++r) {
            const int m = m0 + wy * 32 + mi * 16 + quad * 4 + r;
            float v = acc[mi][r] * scale + off;
            if (z == 0) v = fmaxf(v, 0.f);
            dst[m * 512 + n] = (_Float16)v;
        }
    }
}

// ---------------------------------------------------------------------------
// h2 = relu(h16 @ W2^T + b2) fp32 out. M=512, N=256, K=512. (unchanged)
// ---------------------------------------------------------------------------
__global__ __launch_bounds__(512) void gemm_h2_kernel(
    const _Float16* __restrict__ h16, const float* __restrict__ W2,
    const float* __restrict__ b2, float* __restrict__ h2o)
{
    __shared__ half2v As16[2][16][36];
    __shared__ half2v Bs16[2][16][72];
    __shared__ float Ps[32][68];

    const int t  = threadIdx.x;
    const int gk = t >> 8;
    const int tl = t & 255;
    const int m0 = blockIdx.y * 32;
    const int n0 = blockIdx.x * 64;
    const int tx = tl & 15, ty = tl >> 4;
    const int kb = gk << 8;

    float acc[2][4] = {};

    for (int kc = 0; kc < 256; kc += 32) {
        const int kk = kb + kc;
        if (tl < 128) {
            const int arow = tl >> 2;
            const int ak8  = (tl & 3) << 3;
            const float4 av = *(const float4*)&h16[(m0 + arow) * 512 + kk + ak8];
            const half2v* ap = (const half2v*)&av;
            const int k2 = ak8 >> 1;
            As16[gk][k2 + 0][arow] = ap[0];
            As16[gk][k2 + 1][arow] = ap[1];
            As16[gk][k2 + 2][arow] = ap[2];
            As16[gk][k2 + 3][arow] = ap[3];
        }
        {
            const int brow = tl >> 2;
            const int bk8  = (tl & 3) << 3;
            const float4 bv0 = *(const float4*)&W2[(n0 + brow) * 512 + kk + bk8];
            const float4 bv1 = *(const float4*)&W2[(n0 + brow) * 512 + kk + bk8 + 4];
            const int k2 = bk8 >> 1;
            Bs16[gk][k2 + 0][brow] = cvt2(bv0.x, bv0.y);
            Bs16[gk][k2 + 1][brow] = cvt2(bv0.z, bv0.w);
            Bs16[gk][k2 + 2][brow] = cvt2(bv1.x, bv1.y);
            Bs16[gk][k2 + 3][brow] = cvt2(bv1.z, bv1.w);
        }
        __syncthreads();

        #pragma unroll
        for (int k2 = 0; k2 < 16; ++k2) {
            const half4v a4 = *(const half4v*)&As16[gk][k2][ty * 2];
            const half8v b8 = *(const half8v*)&Bs16[gk][k2][tx * 4];
            const half2v a0 = __builtin_shufflevector(a4, a4, 0, 1);
            const half2v a1 = __builtin_shufflevector(a4, a4, 2, 3);
            const half2v b0 = __builtin_shufflevector(b8, b8, 0, 1);
            const half2v b1h = __builtin_shufflevector(b8, b8, 2, 3);
            const half2v b2h = __builtin_shufflevector(b8, b8, 4, 5);
            const half2v b3h = __builtin_shufflevector(b8, b8, 6, 7);
            acc[0][0] = fdot2(a0, b0, acc[0][0]);
            acc[0][1] = fdot2(a0, b1h, acc[0][1]);
            acc[0][2] = fdot2(a0, b2h, acc[0][2]);
            acc[0][3] = fdot2(a0, b3h, acc[0][3]);
            acc[1][0] = fdot2(a1, b0, acc[1][0]);
            acc[1][1] = fdot2(a1, b1h, acc[1][1]);
            acc[1][2] = fdot2(a1, b2h, acc[1][2]);
            acc[1][3] = fdot2(a1, b3h, acc[1][3]);
        }
        __syncthreads();
    }

    if (gk == 1) {
        #pragma unroll
        for (int i = 0; i < 2; ++i)
            #pragma unroll
            for (int j = 0; j < 4; ++j)
                Ps[ty * 2 + i][tx * 4 + j] = acc[i][j];
    }
    __syncthreads();
    if (gk == 0) {
        const int n = n0 + tx * 4;
        #pragma unroll
        for (int i = 0; i < 2; ++i) {
            const int m = m0 + ty * 2 + i;
            float4 o;
            o.x = fmaxf(acc[i][0] + Ps[ty * 2 + i][tx * 4 + 0] + b2[n + 0], 0.f);
            o.y = fmaxf(acc[i][1] + Ps[ty * 2 + i][tx * 4 + 1] + b2[n + 1], 0.f);
            o.z = fmaxf(acc[i][2] + Ps[ty * 2 + i][tx * 4 + 2] + b2[n + 2], 0.f);
            o.w = fmaxf(acc[i][3] + Ps[ty * 2 + i][tx * 4 + 3] + b2[n + 3], 0.f);
            *(float4*)&h2o[m * 256 + n] = o;
        }
    }
}

// ---------------------------------------------------------------------------
// tail: blocks 0..255 = sim tiles (16x16); blocks 256..319 = head (8 rows ea).
// ---------------------------------------------------------------------------
#define SIMS 260
__global__ __launch_bounds__(512) void tail_kernel(
    const float* __restrict__ h2, const float* __restrict__ W3,
    const float* __restrict__ b3,
    const _Float16* __restrict__ A16, const _Float16* __restrict__ C16,
    const float* __restrict__ ws2, const float* __restrict__ bs2,
    float* __restrict__ out)
{
    __shared__ _Float16 Rs[2][32][SIMS];
    __shared__ _Float16 Qs[2][32][SIMS];
    __shared__ half2v wsh[256];
    __shared__ float Ps[32][33];
    __shared__ float Tt[32][33];

    const int bid = blockIdx.x;
    const int t   = threadIdx.x;

    if (bid >= 256) {
        // ---- head: scores + softmax, one wave per row ----
        const int lane = t & 63;
        const int r = (bid - 256) * 8 + (t >> 6);

        float p[10];
        #pragma unroll
        for (int q = 0; q < 10; ++q) p[q] = 0.f;
        #pragma unroll
        for (int kk = 0; kk < 4; ++kk) {
            const int k = lane + kk * 64;
            const float hv = h2[r * 256 + k];
            #pragma unroll
            for (int q = 0; q < 10; ++q)
                p[q] = fmaf(hv, W3[q * 256 + k], p[q]);
        }
        #pragma unroll
        for (int q = 0; q < 10; ++q) {
            #pragma unroll
            for (int off = 32; off > 0; off >>= 1)
                p[q] += __shfl_down(p[q], off);
        }
        if (lane == 0) {
            float s[10], m = -1e30f;
            #pragma unroll
            for (int q = 0; q < 10; ++q) { s[q] = p[q] + b3[q]; m = fmaxf(m, s[q]); }
            float e[10], sum = 0.f;
            #pragma unroll
            for (int q = 0; q < 10; ++q) { e[q] = __expf(s[q] - m); sum += e[q]; }
            const float inv = 1.f / sum;
            #pragma unroll
            for (int q = 0; q < 10; ++q) {
                out[r * 10 + q] = e[q] * inv;
                out[5120 + r * 10 + q] = s[q];
            }
        }
        return;
    }

    // ---- sim tile ----
    float* __restrict__ S = out + 10240;
    const int gk = t >> 8;
    const int tl = t & 255;
    const int r0 = (bid >> 4) * 32;
    const int q0 = (bid & 15) * 32;
    const bool diag = (r0 == q0);
    const _Float16* RsSrc = (r0 <= q0) ? A16 : C16;
    const _Float16* QsSrc = (r0 <= q0) ? C16 : A16;
    const int kbase = gk << 8;

    if (t < 256) {
        half2v w;
        w.x = (_Float16)ws2[2 * t];
        w.y = (_Float16)ws2[2 * t + 1];
        wsh[t] = w;
    }

    #pragma unroll
    for (int i = 0; i < 4; ++i) {
        const int idx = tl + i * 256;
        const int row = idx >> 5;
        const int c8  = idx & 31;
        const float4 vr = *(const float4*)&RsSrc[(r0 + row) * 512 + kbase + c8 * 8];
        const float4 vq = *(const float4*)&QsSrc[(q0 + row) * 512 + kbase + c8 * 8];
        char* dr = (char*)&Rs[gk][row][0] + c8 * 16;
        ((float2*)dr)[0] = make_float2(vr.x, vr.y);
        ((float2*)dr)[1] = make_float2(vr.z, vr.w);
        char* dq = (char*)&Qs[gk][row][0] + c8 * 16;
        ((float2*)dq)[0] = make_float2(vq.x, vq.y);
        ((float2*)dq)[1] = make_float2(vq.z, vq.w);
    }
    __syncthreads();

    const int tx = tl & 15, ty = tl >> 4;
    const half2v* rp0 = (const half2v*)&Rs[gk][ty * 2][0];
    const half2v* rp1 = (const half2v*)&Rs[gk][ty * 2 + 1][0];
    const half2v* qp0 = (const half2v*)&Qs[gk][tx * 2][0];
    const half2v* qp1 = (const half2v*)&Qs[gk][tx * 2 + 1][0];
    const half2v* wp  = &wsh[gk * 128];
    const half2v z2 = {(_Float16)0, (_Float16)0};

    float a00 = 0.f, a01 = 0.f, a10 = 0.f, a11 = 0.f;
    #pragma unroll 16
    for (int k2 = 0; k2 < 128; ++k2) {
        const half2v r0v = rp0[k2], r1v = rp1[k2];
        const half2v q0v = qp0[k2], q1v = qp1[k2];
        const half2v w2 = wp[k2];
        a00 = fdot2(__builtin_elementwise_max(r0v + q0v, z2), w2, a00);
        a01 = fdot2(__builtin_elementwise_max(r0v + q1v, z2), w2, a01);
        a10 = fdot2(__builtin_elementwise_max(r1v + q0v, z2), w2, a10);
        a11 = fdot2(__builtin_elementwise_max(r1v + q1v, z2), w2, a11);
    }

    if (gk == 1) {
        Ps[ty * 2 + 0][tx * 2 + 0] = a00;
        Ps[ty * 2 + 0][tx * 2 + 1] = a01;
        Ps[ty * 2 + 1][tx * 2 + 0] = a10;
        Ps[ty * 2 + 1][tx * 2 + 1] = a11;
    }
    __syncthreads();

    if (gk == 0) {
        const float bsv = bs2[0];
        float v[2][2];
        v[0][0] = a00 + Ps[ty * 2 + 0][tx * 2 + 0];
        v[0][1] = a01 + Ps[ty * 2 + 0][tx * 2 + 1];
        v[1][0] = a10 + Ps[ty * 2 + 1][tx * 2 + 0];
        v[1][1] = a11 + Ps[ty * 2 + 1][tx * 2 + 1];
        #pragma unroll
        for (int di = 0; di < 2; ++di)
            #pragma unroll
            for (int dj = 0; dj < 2; ++dj)
                v[di][dj] = 1.f / (1.f + __expf(-(v[di][dj] + bsv)));
        if (!diag) {
            #pragma unroll
            for (int di = 0; di < 2; ++di)
                *(float2*)&S[(r0 + ty * 2 + di) * 512 + q0 + tx * 2] =
                    make_float2(v[di][0], v[di][1]);
        } else {
            #pragma unroll
            for (int di = 0; di < 2; ++di)
                #pragma unroll
                for (int dj = 0; dj < 2; ++dj)
                    Tt[ty * 2 + di][tx * 2 + dj] = v[di][dj];
        }
    }
    if (diag) {
        __syncthreads();
        if (gk == 0) {
            #pragma unroll
            for (int di = 0; di < 2; ++di)
                #pragma unroll
                for (int dj = 0; dj < 2; ++dj) {
                    const int rl = ty * 2 + di, ql = tx * 2 + dj;
                    const float o = rl < ql ? Tt[rl][ql] : (rl > ql ? Tt[ql][rl] : 0.f);
                    S[(r0 + rl) * 512 + q0 + ql] = o;
                }
        }
    }
}

extern "C" void kernel_launch(void* const* d_in, const int* in_sizes, int n_in,
                              void* d_out, int out_size, void* d_ws, size_t ws_size,
                              hipStream_t stream)
{
    const float* x   = (const float*)d_in[0];
    const float* W1  = (const float*)d_in[1];
    const float* b1  = (const float*)d_in[2];
    const float* g   = (const float*)d_in[3];
    const float* be  = (const float*)d_in[4];
    const float* mu  = (const float*)d_in[5];
    const float* va  = (const float*)d_in[6];
    const float* W2  = (const float*)d_in[7];
    const float* b2  = (const float*)d_in[8];
    const float* W3  = (const float*)d_in[9];
    const float* b3  = (const float*)d_in[10];
    const float* Wa  = (const float*)d_in[11];
    const float* Wb  = (const float*)d_in[12];
    const float* bs1 = (const float*)d_in[13];
    const float* ws2 = (const float*)d_in[14];
    const float* bs2 = (const float*)d_in[15];

    float* out = (float*)d_out;
    _Float16* h16 = (_Float16*)d_ws;               // 512*512 f16
    float* h2 = (float*)(h16 + 512 * 512);         // 512*256 f32
    _Float16* A16 = (_Float16*)(h2 + 512 * 256);   // 512*512 f16
    _Float16* C16 = A16 + 512 * 512;               // 512*512 f16

    fused3_mfma<<<dim3(16, 8, 3), 256, 0, stream>>>(x, W1, b1, g, be, mu, va,
                                                    Wa, bs1, Wb, h16, A16, C16);
    gemm_h2_kernel<<<dim3(4, 16), 512, 0, stream>>>(h16, W2, b2, h2);
    tail_kernel<<<320, 512, 0, stream>>>(h2, W3, b3, A16, C16, ws2, bs2, out);
}

// Round 9
// 101.032 us; speedup vs baseline: 1.4991x; 1.0990x over previous
//
#include <hip/hip_runtime.h>
#include <math.h>

#define BN_EPS 1e-5f

typedef _Float16 half2v __attribute__((ext_vector_type(2)));
typedef _Float16 half8v __attribute__((ext_vector_type(8)));
typedef __fp16 fp16x8 __attribute__((ext_vector_type(8)));
typedef float floatx4 __attribute__((ext_vector_type(4)));

__device__ __forceinline__ float fdot2(half2v a, half2v b, float c) {
    return __builtin_amdgcn_fdot2(a, b, c, false);
}
__device__ __forceinline__ half2v cvt2(float a, float b) {
    return __builtin_bit_cast(half2v, __builtin_amdgcn_cvt_pkrtz(a, b));
}
__device__ __forceinline__ floatx4 mfma16(half8v a, half8v b, floatx4 c) {
    return __builtin_amdgcn_mfma_f32_16x16x32_f16(
        __builtin_bit_cast(fp16x8, a), __builtin_bit_cast(fp16x8, b), c, 0, 0, 0);
}

// ---------------------------------------------------------------------------
// fused3 (MFMA): unchanged from R8 (verified).
// ---------------------------------------------------------------------------
__global__ __launch_bounds__(256) void fused3_mfma(
    const float* __restrict__ x,
    const float* __restrict__ W1, const float* __restrict__ b1,
    const float* __restrict__ g, const float* __restrict__ be,
    const float* __restrict__ mu, const float* __restrict__ va,
    const float* __restrict__ Wa, const float* __restrict__ bs1,
    const float* __restrict__ Wb,
    _Float16* __restrict__ h16, _Float16* __restrict__ A16,
    _Float16* __restrict__ C16)
{
    __shared__ _Float16 Xs[64][264];
    __shared__ _Float16 Ws[32][264];

    const int t  = threadIdx.x;
    const int n0 = blockIdx.x * 32;
    const int m0 = blockIdx.y * 64;
    const int z  = blockIdx.z;
    const float* __restrict__ Wp = (z == 0) ? W1 : (z == 1 ? Wa : Wb);

    #pragma unroll
    for (int i = 0; i < 16; ++i) {
        const int cidx = t + i * 256;
        const int row = cidx >> 6;
        const int c4  = cidx & 63;
        const float4 v = *(const float4*)&x[(m0 + row) * 256 + c4 * 4];
        *(half2v*)&Xs[row][c4 * 4 + 0] = cvt2(v.x, v.y);
        *(half2v*)&Xs[row][c4 * 4 + 2] = cvt2(v.z, v.w);
    }
    #pragma unroll
    for (int i = 0; i < 8; ++i) {
        const int cidx = t + i * 256;
        const int row = cidx >> 6;
        const int c4  = cidx & 63;
        const float4 v = *(const float4*)&Wp[(n0 + row) * 256 + c4 * 4];
        *(half2v*)&Ws[row][c4 * 4 + 0] = cvt2(v.x, v.y);
        *(half2v*)&Ws[row][c4 * 4 + 2] = cvt2(v.z, v.w);
    }
    __syncthreads();

    const int wave = t >> 6;
    const int lane = t & 63;
    const int wy = wave >> 1, wx = wave & 1;
    const int lrow = lane & 15;
    const int quad = lane >> 4;
    const int kq = quad * 8;

    floatx4 acc[2] = {{0.f, 0.f, 0.f, 0.f}, {0.f, 0.f, 0.f, 0.f}};

    #pragma unroll
    for (int kc = 0; kc < 256; kc += 32) {
        const half8v a0 = *(const half8v*)&Xs[wy * 32 + lrow][kc + kq];
        const half8v a1 = *(const half8v*)&Xs[wy * 32 + 16 + lrow][kc + kq];
        const half8v b0 = *(const half8v*)&Ws[wx * 16 + lrow][kc + kq];
        acc[0] = mfma16(a0, b0, acc[0]);
        acc[1] = mfma16(a1, b0, acc[1]);
    }

    const int n = n0 + wx * 16 + lrow;
    float scale, off;
    if (z == 0) {
        const float s = g[n] * rsqrtf(va[n] + BN_EPS);
        scale = s;
        off = (b1[n] - mu[n]) * s + be[n];
    } else if (z == 1) {
        scale = 1.f;
        off = bs1[n];
    } else {
        scale = 1.f;
        off = 0.f;
    }
    _Float16* __restrict__ dst = (z == 0) ? h16 : (z == 1 ? A16 : C16);
    #pragma unroll
    for (int mi = 0; mi < 2; ++mi) {
        #pragma unroll
        for (int r = 0; r < 4; ++r) {
            const int m = m0 + wy * 32 + mi * 16 + quad * 4 + r;
            float v = acc[mi][r] * scale + off;
            if (z == 0) v = fmaxf(v, 0.f);
            dst[m * 512 + n] = (_Float16)v;
        }
    }
}

// ---------------------------------------------------------------------------
// h2 (MFMA) = relu(h16 @ W2^T + b2) fp32. M=512,N=256,K=512.
// 32m x 32n tile, grid (8,16)=128 blocks, 256 thr = 4 waves 2x2, full-K LDS
// strips stride 520 halfs (1040B: 16B-aligned, rows == 4 words mod 32 banks
// -> 2-way-free b128 frag reads). 16 MFMA per wave.
// ---------------------------------------------------------------------------
__global__ __launch_bounds__(256) void h2_mfma(
    const _Float16* __restrict__ h16, const float* __restrict__ W2,
    const float* __restrict__ b2, float* __restrict__ h2o)
{
    __shared__ _Float16 Xs[32][520];
    __shared__ _Float16 Ws[32][520];

    const int t  = threadIdx.x;
    const int n0 = blockIdx.x * 32;
    const int m0 = blockIdx.y * 32;

    // Stage X (h16 f16): 32 rows x 64 half8-chunks = 2048 (8/thread)
    #pragma unroll
    for (int i = 0; i < 8; ++i) {
        const int cidx = t + i * 256;
        const int row = cidx >> 6;
        const int c8  = cidx & 63;
        const float4 v = *(const float4*)&h16[(m0 + row) * 512 + c8 * 8];
        *(half8v*)&Xs[row][c8 * 8] = __builtin_bit_cast(half8v, v);
    }
    // Stage W (W2 fp32 -> f16): 32 rows x 64 chunks (8/thread)
    #pragma unroll
    for (int i = 0; i < 8; ++i) {
        const int cidx = t + i * 256;
        const int row = cidx >> 6;
        const int c8  = cidx & 63;
        const float4 v0 = *(const float4*)&W2[(n0 + row) * 512 + c8 * 8];
        const float4 v1 = *(const float4*)&W2[(n0 + row) * 512 + c8 * 8 + 4];
        *(half2v*)&Ws[row][c8 * 8 + 0] = cvt2(v0.x, v0.y);
        *(half2v*)&Ws[row][c8 * 8 + 2] = cvt2(v0.z, v0.w);
        *(half2v*)&Ws[row][c8 * 8 + 4] = cvt2(v1.x, v1.y);
        *(half2v*)&Ws[row][c8 * 8 + 6] = cvt2(v1.z, v1.w);
    }
    __syncthreads();

    const int wave = t >> 6;
    const int lane = t & 63;
    const int wy = wave >> 1, wx = wave & 1;
    const int lrow = lane & 15;
    const int quad = lane >> 4;
    const int kq = quad * 8;

    floatx4 acc = {0.f, 0.f, 0.f, 0.f};
    #pragma unroll
    for (int kc = 0; kc < 512; kc += 32) {
        const half8v a = *(const half8v*)&Xs[wy * 16 + lrow][kc + kq];
        const half8v b = *(const half8v*)&Ws[wx * 16 + lrow][kc + kq];
        acc = mfma16(a, b, acc);
    }

    const int n = n0 + wx * 16 + lrow;
    const float bb = b2[n];
    #pragma unroll
    for (int r = 0; r < 4; ++r) {
        const int m = m0 + wy * 16 + quad * 4 + r;
        h2o[m * 256 + n] = fmaxf(acc[r] + bb, 0.f);
    }
}

// ---------------------------------------------------------------------------
// tail: blocks 0..527 = sim triangle tiles 16x16 (tile b -> it<=jt);
// blocks 528..655 = head (4 rows each). 256 threads.
// Sim: thread (ty,tx) owns output (r0+ty, q0+tx), full 512-k chain.
// Triangle only (no duplicate compute); mirror via LDS transpose, coalesced.
// ---------------------------------------------------------------------------
__global__ __launch_bounds__(256) void tail_kernel(
    const float* __restrict__ h2, const float* __restrict__ W3,
    const float* __restrict__ b3,
    const _Float16* __restrict__ A16, const _Float16* __restrict__ C16,
    const float* __restrict__ ws2, const float* __restrict__ bs2,
    float* __restrict__ out)
{
    __shared__ _Float16 Rs[16][520];
    __shared__ _Float16 Qs[16][520];
    __shared__ half2v wsh[256];
    __shared__ float Tt[16][17];

    const int bid = blockIdx.x;
    const int t   = threadIdx.x;

    if (bid >= 528) {
        // ---- head: one wave per row, 4 rows/block ----
        const int lane = t & 63;
        const int r = (bid - 528) * 4 + (t >> 6);

        float p[10];
        #pragma unroll
        for (int q = 0; q < 10; ++q) p[q] = 0.f;
        #pragma unroll
        for (int kk = 0; kk < 4; ++kk) {
            const int k = lane + kk * 64;
            const float hv = h2[r * 256 + k];
            #pragma unroll
            for (int q = 0; q < 10; ++q)
                p[q] = fmaf(hv, W3[q * 256 + k], p[q]);
        }
        #pragma unroll
        for (int q = 0; q < 10; ++q) {
            #pragma unroll
            for (int off = 32; off > 0; off >>= 1)
                p[q] += __shfl_down(p[q], off);
        }
        if (lane == 0) {
            float s[10], m = -1e30f;
            #pragma unroll
            for (int q = 0; q < 10; ++q) { s[q] = p[q] + b3[q]; m = fmaxf(m, s[q]); }
            float e[10], sum = 0.f;
            #pragma unroll
            for (int q = 0; q < 10; ++q) { e[q] = __expf(s[q] - m); sum += e[q]; }
            const float inv = 1.f / sum;
            #pragma unroll
            for (int q = 0; q < 10; ++q) {
                out[r * 10 + q] = e[q] * inv;
                out[5120 + r * 10 + q] = s[q];
            }
        }
        return;
    }

    // ---- sim triangle tile: b -> (it, jt) with it <= jt, 32 tiles of 16 ----
    float* __restrict__ S = out + 10240;
    int jt = 0;
    {   // largest jt with jt*(jt+1)/2 <= bid
        int b = bid;
        while ((jt + 1) * (jt + 2) / 2 <= b) ++jt;
    }
    const int it = bid - jt * (jt + 1) / 2;
    const int r0 = it * 16, q0 = jt * 16;
    const bool diag = (it == jt);

    // weights: all 512 k as half2
    {
        half2v w;
        w.x = (_Float16)ws2[2 * t];
        w.y = (_Float16)ws2[2 * t + 1];
        wsh[t] = w;
    }
    // Stage rows: A-rows r0.. (Rs) and C-rows q0.. (Qs), 16 rows x 64 chunks
    #pragma unroll
    for (int i = 0; i < 4; ++i) {
        const int cidx = t + i * 256;
        const int row = cidx >> 6;
        const int c8  = cidx & 63;
        const float4 vr = *(const float4*)&A16[(r0 + row) * 512 + c8 * 8];
        const float4 vq = *(const float4*)&C16[(q0 + row) * 512 + c8 * 8];
        *(half8v*)&Rs[row][c8 * 8] = __builtin_bit_cast(half8v, vr);
        *(half8v*)&Qs[row][c8 * 8] = __builtin_bit_cast(half8v, vq);
    }
    __syncthreads();

    const int tx = t & 15, ty = t >> 4;
    const half2v* rp = (const half2v*)&Rs[ty][0];
    const half2v* qp = (const half2v*)&Qs[tx][0];
    const half2v z2 = {(_Float16)0, (_Float16)0};

    float a0 = 0.f;
    #pragma unroll 8
    for (int k2 = 0; k2 < 256; ++k2) {
        a0 = fdot2(__builtin_elementwise_max(rp[k2] + qp[k2], z2), wsh[k2], a0);
    }
    const float v = 1.f / (1.f + __expf(-(a0 + bs2[0])));

    Tt[ty][tx] = v;
    __syncthreads();

    if (diag) {
        const int r = r0 + ty, q = q0 + tx;
        const float o = (r < q) ? Tt[ty][tx] : (r > q ? Tt[tx][ty] : 0.f);
        S[r * 512 + q] = o;
    } else {
        S[(r0 + ty) * 512 + q0 + tx] = v;                 // direct
        S[(q0 + ty) * 512 + r0 + tx] = Tt[tx][ty];        // mirror (transposed)
    }
}

extern "C" void kernel_launch(void* const* d_in, const int* in_sizes, int n_in,
                              void* d_out, int out_size, void* d_ws, size_t ws_size,
                              hipStream_t stream)
{
    const float* x   = (const float*)d_in[0];
    const float* W1  = (const float*)d_in[1];
    const float* b1  = (const float*)d_in[2];
    const float* g   = (const float*)d_in[3];
    const float* be  = (const float*)d_in[4];
    const float* mu  = (const float*)d_in[5];
    const float* va  = (const float*)d_in[6];
    const float* W2  = (const float*)d_in[7];
    const float* b2  = (const float*)d_in[8];
    const float* W3  = (const float*)d_in[9];
    const float* b3  = (const float*)d_in[10];
    const float* Wa  = (const float*)d_in[11];
    const float* Wb  = (const float*)d_in[12];
    const float* bs1 = (const float*)d_in[13];
    const float* ws2 = (const float*)d_in[14];
    const float* bs2 = (const float*)d_in[15];

    float* out = (float*)d_out;
    _Float16* h16 = (_Float16*)d_ws;               // 512*512 f16
    float* h2 = (float*)(h16 + 512 * 512);         // 512*256 f32
    _Float16* A16 = (_Float16*)(h2 + 512 * 256);   // 512*512 f16
    _Float16* C16 = A16 + 512 * 512;               // 512*512 f16

    fused3_mfma<<<dim3(16, 8, 3), 256, 0, stream>>>(x, W1, b1, g, be, mu, va,
                                                    Wa, bs1, Wb, h16, A16, C16);
    h2_mfma<<<dim3(8, 16), 256, 0, stream>>>(h16, W2, b2, h2);
    tail_kernel<<<656, 256, 0, stream>>>(h2, W3, b3, A16, C16, ws2, bs2, out);
}